// Round 1
// baseline (435.902 us; speedup 1.0000x reference)
//
#include <hip/hip_runtime.h>
#include <math.h>

#define NN 16
#define GG 4096
#define GP 2              // grid points per block
#define STR 68            // LDS row stride (floats): 68%32=4 -> max 2-way bank alias (free)
#define NWG (GG / GP)     // 2048 blocks

// In-place Gauss-Jordan inverse (no pivoting; valid: matrices are I + small
// perturbation, or SPD). Returns sum of log|pivot| = log|det|.
__device__ __forceinline__ double gj_inv8(double M[8][8]) {
    double ld = 0.0;
#pragma unroll
    for (int k = 0; k < 8; ++k) {
        double p = M[k][k];
        ld += log(fabs(p));
        double ip = 1.0 / p;
        M[k][k] = 1.0;
#pragma unroll
        for (int jj = 0; jj < 8; ++jj) M[k][jj] *= ip;
#pragma unroll
        for (int ii = 0; ii < 8; ++ii) {
            if (ii == k) continue;
            double d = M[ii][k];
            M[ii][k] = 0.0;
#pragma unroll
            for (int jj = 0; jj < 8; ++jj) M[ii][jj] -= M[k][jj] * d;
        }
    }
    return ld;
}

// Determinant-only LU (no pivoting). Returns log|det|.
__device__ __forceinline__ double lu_logdet8(double M[8][8]) {
    double ld = 0.0;
#pragma unroll
    for (int k = 0; k < 8; ++k) {
        double p = M[k][k];
        ld += log(fabs(p));
        double ip = 1.0 / p;
#pragma unroll
        for (int ii = k + 1; ii < 8; ++ii) {
            double f = M[ii][k] * ip;
#pragma unroll
            for (int jj = k + 1; jj < 8; ++jj) M[ii][jj] -= f * M[k][jj];
        }
    }
    return ld;
}

__global__ __launch_bounds__(256, 2) void pairkl_kernel(
    const float* __restrict__ omega, const float* __restrict__ links,
    const float* __restrict__ mu, const float* __restrict__ sigma,
    float* __restrict__ out) {
    __shared__ float sh_om[GP][NN][STR];  // omega
    __shared__ float sh_V [GP][NN][STR];  // V = l0 + l1 - I
    __shared__ float sh_wv[GP][NN][STR];  // Winv = (omega V)^{-1}
    __shared__ float sh_sg[GP][NN][STR];  // sigma_q
    __shared__ float sh_si[GP][NN][STR];  // sigma_q^{-1}
    __shared__ float sh_mu[GP][NN][9];    // stride 9: conflict-free over j
    __shared__ float sh_sc[GP][NN][4];    // scalars

    const int bid  = blockIdx.x;
    const int work = (bid & 7) * (NWG / 8) + (bid >> 3);  // XCD-bijective swizzle
    const int g0   = work * GP;
    const int t    = threadIdx.x;

    // ---- Phase 0: coalesced staging ----
    for (int idx = t; idx < GP * NN * 64; idx += 256) {
        int e = idx & 63, i = (idx >> 6) & (NN - 1), gl = idx >> 10;
        int g = g0 + gl;
        int base = (i * GG + g) * 64 + e;
        sh_om[gl][i][e] = omega[base];
        sh_sg[gl][i][e] = sigma[base];
        float l0 = links[((i * 2 + 0) * GG + g) * 64 + e];
        float l1 = links[((i * 2 + 1) * GG + g) * 64 + e];
        float iv = ((e >> 3) == (e & 7)) ? 1.0f : 0.0f;
        sh_V[gl][i][e] = l0 + l1 - iv;
    }
    for (int idx = t; idx < GP * NN * 8; idx += 256) {
        int c = idx & 7, i = (idx >> 3) & (NN - 1), gl = idx >> 7;
        sh_mu[gl][i][c] = mu[(i * GG + g0 + gl) * 8 + c];
    }
    __syncthreads();

    // ---- Phase 1: per-(gl,i) inversions, f64, 2 threads per item ----
    if (t < 2 * GP * NN) {
        const bool evn = (t & 1) == 0;
        const int p = t >> 1;
        const int gl = p >> 4, i = p & (NN - 1);
        double M[8][8];
        if (evn) {
            // M = T = omega @ V
#pragma unroll
            for (int a = 0; a < 8; ++a) {
                float o[8];
#pragma unroll
                for (int b = 0; b < 8; ++b) o[b] = sh_om[gl][i][a * 8 + b];
#pragma unroll
                for (int c = 0; c < 8; ++c) {
                    double s = 0.0;
#pragma unroll
                    for (int b = 0; b < 8; ++b)
                        s += (double)o[b] * (double)sh_V[gl][i][b * 8 + c];
                    M[a][c] = s;
                }
            }
        } else {
#pragma unroll
            for (int e = 0; e < 64; ++e) M[e >> 3][e & 7] = (double)sh_sg[gl][i][e];
        }
        double ld = gj_inv8(M);
        if (evn) {
#pragma unroll
            for (int e = 0; e < 64; ++e) sh_wv[gl][i][e] = (float)M[e >> 3][e & 7];
            sh_sc[gl][i][0] = (float)ld;  // ldT
        } else {
#pragma unroll
            for (int e = 0; e < 64; ++e) sh_si[gl][i][e] = (float)M[e >> 3][e & 7];
#pragma unroll
            for (int e = 0; e < 64; ++e) M[e >> 3][e & 7] = (double)sh_om[gl][i][e];
            double ldo = lu_logdet8(M);
            sh_sc[gl][i][1] = (float)ld;   // ld1
            sh_sc[gl][i][2] = (float)ldo;  // ldo
        }
    }
    __syncthreads();
    if (t < GP * NN) {
        int gl = t >> 4, i = t & (NN - 1);
        float ldT = sh_sc[gl][i][0], ld1 = sh_sc[gl][i][1], ldo = sh_sc[gl][i][2];
        sh_sc[gl][i][0] = 2.0f * ldT - ld1;  // a_i
        sh_sc[gl][i][1] = ld1 - 2.0f * ldo;  // b_j
    }
    __syncthreads();

    // ---- Phase 2: one (i,j) pair per thread, loop over gl ----
    const int i = t >> 4, j = t & (NN - 1);
    float res[GP];
#pragma unroll
    for (int gl = 0; gl < GP; ++gl) {
        float B[64];
        {
            float Wr[64];
#pragma unroll
            for (int e = 0; e < 64; ++e) Wr[e] = sh_wv[gl][i][e];
#pragma unroll
            for (int a = 0; a < 8; ++a) {
                float o[8];
#pragma unroll
                for (int b = 0; b < 8; ++b) o[b] = sh_om[gl][j][a * 8 + b];
#pragma unroll
                for (int c = 0; c < 8; ++c) {
                    float s = 0.f;
#pragma unroll
                    for (int b = 0; b < 8; ++b) s = fmaf(o[b], Wr[b * 8 + c], s);
                    B[a * 8 + c] = s;  // B = omega_j @ Winv_i
                }
            }
        }
        float Sr[64];
#pragma unroll
        for (int e = 0; e < 64; ++e) Sr[e] = sh_sg[gl][i][e];
        float tr = 0.f;
#pragma unroll
        for (int b = 0; b < 8; ++b) {
            float sjr[8];
#pragma unroll
            for (int a = 0; a < 8; ++a) sjr[a] = sh_si[gl][j][b * 8 + a];
#pragma unroll
            for (int c = 0; c < 8; ++c) {
                float x = 0.f, y = 0.f;
#pragma unroll
                for (int d = 0; d < 8; ++d) x = fmaf(B[b * 8 + d], Sr[d * 8 + c], x);
#pragma unroll
                for (int a = 0; a < 8; ++a) y = fmaf(sjr[a], B[a * 8 + c], y);
                tr = fmaf(x, y, tr);  // tr(sj_inv * B sig_i B^T)
            }
        }
        float mi[8];
#pragma unroll
        for (int c = 0; c < 8; ++c) mi[c] = sh_mu[gl][i][c];
        float v[8];
#pragma unroll
        for (int a = 0; a < 8; ++a) {
            float s = sh_mu[gl][j][a];
#pragma unroll
            for (int c = 0; c < 8; ++c) s = fmaf(-B[a * 8 + c], mi[c], s);
            v[a] = s;  // v = mu_j - B mu_i
        }
        float quad = 0.f;
#pragma unroll
        for (int a = 0; a < 8; ++a) {
            float s = 0.f;
#pragma unroll
            for (int b = 0; b < 8; ++b) s = fmaf(sh_si[gl][j][a * 8 + b], v[b], s);
            quad = fmaf(v[a], s, quad);
        }
        float E = 0.5f * (tr + quad - 8.0f + sh_sc[gl][i][0] + sh_sc[gl][j][1]);
        res[gl] = (i == j) ? 0.0f : E;
    }
    *reinterpret_cast<float2*>(&out[(i * NN + j) * GG + g0]) =
        make_float2(res[0], res[1]);
}

extern "C" void kernel_launch(void* const* d_in, const int* in_sizes, int n_in,
                              void* d_out, int out_size, void* d_ws, size_t ws_size,
                              hipStream_t stream) {
    const float* omega = (const float*)d_in[0];
    const float* links = (const float*)d_in[1];
    const float* mu    = (const float*)d_in[2];
    const float* sigma = (const float*)d_in[3];
    float* out = (float*)d_out;
    hipLaunchKernelGGL(pairkl_kernel, dim3(NWG), dim3(256), 0, stream,
                       omega, links, mu, sigma, out);
}

// Round 2
// 48.116 us; speedup vs baseline: 9.0595x; 9.0595x over previous
//
#include <hip/hip_runtime.h>
#include <math.h>

#define NN 16
#define GG 4096
#define GP 2              // grid points per block
#define STR 68            // LDS row stride (floats): 16B-aligned rows, banks spread (4j mod 32)
#define NWG (GG / GP)     // 2048 blocks

// In-place f32 Gauss-Jordan inverse (no pivoting; valid: matrices are
// I + small perturbation, or SPD diag-dominant). Returns log|det|.
__device__ __forceinline__ float gj_inv8(float M[8][8]) {
    float ld = 0.0f;
#pragma unroll
    for (int k = 0; k < 8; ++k) {
        float p = M[k][k];
        ld += logf(fabsf(p));
        float ip = 1.0f / p;
        M[k][k] = 1.0f;
#pragma unroll
        for (int jj = 0; jj < 8; ++jj) M[k][jj] *= ip;
#pragma unroll
        for (int ii = 0; ii < 8; ++ii) {
            if (ii == k) continue;
            float d = M[ii][k];
            M[ii][k] = 0.0f;
#pragma unroll
            for (int jj = 0; jj < 8; ++jj) M[ii][jj] = fmaf(-M[k][jj], d, M[ii][jj]);
        }
    }
    return ld;
}

// Determinant-only LU (no pivoting). Returns log|det|.
__device__ __forceinline__ float lu_logdet8(float M[8][8]) {
    float ld = 0.0f;
#pragma unroll
    for (int k = 0; k < 8; ++k) {
        float p = M[k][k];
        ld += logf(fabsf(p));
        float ip = 1.0f / p;
#pragma unroll
        for (int ii = k + 1; ii < 8; ++ii) {
            float f = M[ii][k] * ip;
#pragma unroll
            for (int jj = k + 1; jj < 8; ++jj) M[ii][jj] = fmaf(-f, M[k][jj], M[ii][jj]);
        }
    }
    return ld;
}

__global__ __launch_bounds__(256, 3) void pairkl_kernel(
    const float* __restrict__ omega, const float* __restrict__ links,
    const float* __restrict__ mu, const float* __restrict__ sigma,
    float* __restrict__ out) {
    // Overlays: sh_V holds V in phase 1a, then P_j. sh_om holds omega, then Q_i.
    __shared__ __align__(16) float sh_om[GP][NN][STR];  // omega -> Q
    __shared__ __align__(16) float sh_sg[GP][NN][STR];  // sigma_q
    __shared__ __align__(16) float sh_V [GP][NN][STR];  // V -> P
    __shared__ __align__(16) float sh_wv[GP][NN][STR];  // Winv = (omega V)^{-1}
    __shared__ __align__(16) float sh_si[GP][NN][STR];  // sigma_q^{-1}
    __shared__ float sh_mu[GP][NN][9];
    __shared__ float sh_u [GP][NN][9];                  // u_i = Winv mu
    __shared__ float sh_w [GP][NN][9];                  // w_j = om^T si mu
    __shared__ float sh_sc[GP][NN][4];                  // ldT,ld1,ldo -> a_i, s_j

#define sh_P sh_V
#define sh_Q sh_om

    const int bid  = blockIdx.x;
    const int work = (bid & 7) * (NWG / 8) + (bid >> 3);  // XCD-bijective swizzle
    const int g0   = work * GP;
    const int t    = threadIdx.x;

    // ---- Phase 0: coalesced staging ----
    for (int idx = t; idx < GP * NN * 64; idx += 256) {
        int e = idx & 63, i = (idx >> 6) & (NN - 1), gl = idx >> 10;
        int g = g0 + gl;
        int base = (i * GG + g) * 64 + e;
        sh_om[gl][i][e] = omega[base];
        sh_sg[gl][i][e] = sigma[base];
        float l0 = links[((i * 2 + 0) * GG + g) * 64 + e];
        float l1 = links[((i * 2 + 1) * GG + g) * 64 + e];
        float iv = ((e >> 3) == (e & 7)) ? 1.0f : 0.0f;
        sh_V[gl][i][e] = l0 + l1 - iv;
    }
    if (t < GP * NN * 8) {
        int c = t & 7, i = (t >> 3) & (NN - 1), gl = t >> 7;
        sh_mu[gl][i][c] = mu[(i * GG + g0 + gl) * 8 + c];
    }
    __syncthreads();

    // ---- Phase 1a: per-(gl,i) f32 inversions, 2 threads per item ----
    if (t < 2 * GP * NN) {
        const bool evn = (t & 1) == 0;
        const int p = t >> 1;
        const int gl = p >> 4, i = p & (NN - 1);
        float M[8][8];
        if (evn) {
            // M = T = omega @ V
#pragma unroll
            for (int a = 0; a < 8; ++a) {
                float o[8];
#pragma unroll
                for (int b = 0; b < 8; ++b) o[b] = sh_om[gl][i][a * 8 + b];
#pragma unroll
                for (int c = 0; c < 8; ++c) {
                    float s = 0.f;
#pragma unroll
                    for (int b = 0; b < 8; ++b) s = fmaf(o[b], sh_V[gl][i][b * 8 + c], s);
                    M[a][c] = s;
                }
            }
            float ld = gj_inv8(M);
#pragma unroll
            for (int e = 0; e < 64; ++e) sh_wv[gl][i][e] = M[e >> 3][e & 7];
            sh_sc[gl][i][0] = ld;  // ldT
        } else {
#pragma unroll
            for (int e = 0; e < 64; ++e) M[e >> 3][e & 7] = sh_sg[gl][i][e];
            float ld = gj_inv8(M);
#pragma unroll
            for (int e = 0; e < 64; ++e) sh_si[gl][i][e] = M[e >> 3][e & 7];
#pragma unroll
            for (int e = 0; e < 64; ++e) M[e >> 3][e & 7] = sh_om[gl][i][e];
            float ldo = lu_logdet8(M);
            sh_sc[gl][i][1] = ld;   // ld1 = logdet sigma
            sh_sc[gl][i][2] = ldo;  // logdet omega
        }
    }
    __syncthreads();

    // ---- Phase 1b-1: P = om^T si om (-> sh_V), u, w, scalars. 8 thr/item ----
    {
        const int item = t >> 3, r = t & 7;
        const int gl = item >> 4, i = item & (NN - 1);
        const float* om = &sh_om[gl][i][0];
        const float* si = &sh_si[gl][i][0];
        const float* wv = &sh_wv[gl][i][0];
        const float* mq = &sh_mu[gl][i][0];
        float t1[8];
#pragma unroll
        for (int b = 0; b < 8; ++b) {
            float s = 0.f;
#pragma unroll
            for (int a = 0; a < 8; ++a) s = fmaf(om[a * 8 + r], si[a * 8 + b], s);
            t1[b] = s;  // (om^T si)[r,b]
        }
        float prow[8];
#pragma unroll
        for (int c = 0; c < 8; ++c) {
            float s = 0.f;
#pragma unroll
            for (int b = 0; b < 8; ++b) s = fmaf(t1[b], om[b * 8 + c], s);
            prow[c] = s;
        }
        float uu = 0.f, ww = 0.f;
#pragma unroll
        for (int b = 0; b < 8; ++b) {
            uu = fmaf(wv[r * 8 + b], mq[b], uu);
            ww = fmaf(t1[b], mq[b], ww);
        }
        float cc = 0.f, a_i = 0.f, s_i = 0.f;
        if (r == 0) {
#pragma unroll
            for (int a = 0; a < 8; ++a) {
                float s = 0.f;
#pragma unroll
                for (int b = 0; b < 8; ++b) s = fmaf(si[a * 8 + b], mq[b], s);
                cc = fmaf(mq[a], s, cc);
            }
            float ldT = sh_sc[gl][i][0], ld1 = sh_sc[gl][i][1], ldo = sh_sc[gl][i][2];
            a_i = 2.f * ldT - ld1;
            s_i = ld1 - 2.f * ldo + cc - 8.0f;
        }
        __syncthreads();  // all om/V reads done; now write P (over V) + u,w,sc
#pragma unroll
        for (int c = 0; c < 8; ++c) sh_P[gl][i][r * 8 + c] = prow[c];
        sh_u[gl][i][r] = uu;
        sh_w[gl][i][r] = ww;
        if (r == 0) { sh_sc[gl][i][0] = a_i; sh_sc[gl][i][1] = s_i; }
        __syncthreads();

        // ---- Phase 1b-2: Q = wv sg wv^T (-> sh_om) ----
        const float* sg = &sh_sg[gl][i][0];
        float t2[8];
#pragma unroll
        for (int d = 0; d < 8; ++d) {
            float s = 0.f;
#pragma unroll
            for (int b = 0; b < 8; ++b) s = fmaf(wv[r * 8 + b], sg[b * 8 + d], s);
            t2[d] = s;
        }
        float qrow[8];
#pragma unroll
        for (int c = 0; c < 8; ++c) {
            float s = 0.f;
#pragma unroll
            for (int d = 0; d < 8; ++d) s = fmaf(t2[d], wv[c * 8 + d], s);
            qrow[c] = s;
        }
        __syncthreads();  // all om reads done; now write Q over om
#pragma unroll
        for (int c = 0; c < 8; ++c) sh_Q[gl][i][r * 8 + c] = qrow[c];
    }
    __syncthreads();

    // ---- Phase 2: one (i,j) pair per thread ----
    const int i = t >> 4, j = t & (NN - 1);
    float res[GP];
#pragma unroll
    for (int gl = 0; gl < GP; ++gl) {
        const float* Pj = &sh_P[gl][j][0];
        const float* Qi = &sh_Q[gl][i][0];
        float u[8];
#pragma unroll
        for (int b = 0; b < 8; ++b) u[b] = sh_u[gl][i][b];
        float tr = 0.f, upu = 0.f;
#pragma unroll
        for (int a = 0; a < 8; ++a) {
            float s = 0.f;
#pragma unroll
            for (int b = 0; b < 8; ++b) {
                float p = Pj[a * 8 + b];
                tr = fmaf(p, Qi[a * 8 + b], tr);
                s  = fmaf(p, u[b], s);
            }
            upu = fmaf(u[a], s, upu);
        }
        float wu = 0.f;
#pragma unroll
        for (int a = 0; a < 8; ++a) wu = fmaf(sh_w[gl][j][a], u[a], wu);
        float E = 0.5f * (tr + upu - 2.f * wu + sh_sc[gl][i][0] + sh_sc[gl][j][1]);
        res[gl] = (i == j) ? 0.0f : E;
    }
    *reinterpret_cast<float2*>(&out[(i * NN + j) * GG + g0]) =
        make_float2(res[0], res[1]);
}

extern "C" void kernel_launch(void* const* d_in, const int* in_sizes, int n_in,
                              void* d_out, int out_size, void* d_ws, size_t ws_size,
                              hipStream_t stream) {
    const float* omega = (const float*)d_in[0];
    const float* links = (const float*)d_in[1];
    const float* mu    = (const float*)d_in[2];
    const float* sigma = (const float*)d_in[3];
    float* out = (float*)d_out;
    hipLaunchKernelGGL(pairkl_kernel, dim3(NWG), dim3(256), 0, stream,
                       omega, links, mu, sigma, out);
}